// Round 8
// baseline (276.141 us; speedup 1.0000x reference)
//
#include <hip/hip_runtime.h>

// RNNNet: 7-layer tanh RNN, N=65536, T=28, V=28, H=64, 10-class head.
// R8: R7 (time-outer/layer-inner, barrier-free, all weights LDS-resident)
//     + TWO independent sequence groups per wave (32 seqs/wave, grid 256):
//     two parallel dependency chains hide MFMA/tanh/DS-roundtrip latency that
//     R7 left uncovered (40% no-issue cycles at 2 waves/SIMD); weight/bias
//     fragments read once, shared by both groups. Time-pair dropped (was
//     serially coupled via hh) to keep VGPR < 256. Numerics identical to R7.
// GEMMs via mfma_f32_16x16x32_bf16, swapped operands: D[j][s] = W x h^T.

namespace {

typedef __attribute__((ext_vector_type(8))) short bf16x8;
typedef __attribute__((ext_vector_type(4))) float f32x4;
typedef __attribute__((ext_vector_type(4))) unsigned u32x4;

constexpr int WST = 0;                  // 7 layers x (ih 8KB + hh 8KB) bf16 swz
constexpr int SCR = 7 * 16384;          // 114688: 16 relayout rows (8 waves x 2 grp)
constexpr int WCL = SCR + 16 * 2048;    // 147456: Wc padded [16][64] bf16
constexpr int BIA = WCL + 2048;         // 149504: (bih+bhh)*K f32 [7][64]
constexpr int BCV = BIA + 1792;         // 151296: bc f32 padded [16]
constexpr int LDS_TOTAL = BCV + 64;     // 151360 (< 163840, 1 block/CU)

constexpr float TANH_K = 2.8853900817779268f;   // 2/ln(2)

// input pre-scaled by 2/ln2: tanh(x) = 1 - 2/(2^a + 1). 1-ulp HW ops, no bias.
__device__ __forceinline__ float tanh_pre(float a) {
    float z = __builtin_amdgcn_exp2f(a);
    return fmaf(-2.f, __builtin_amdgcn_rcpf(z + 1.f), 1.f);
}
__device__ __forceinline__ unsigned cvt_pk(float a, float b) {
    unsigned r;                              // lo=bf16(a), hi=bf16(b), RNE
    asm("v_cvt_pk_bf16_f32 %0, %1, %2" : "=v"(r) : "v"(a), "v"(b));
    return r;
}
__device__ __forceinline__ int4 pack8s(const float* v, float s) {
    return make_int4((int)cvt_pk(v[0] * s, v[1] * s), (int)cvt_pk(v[2] * s, v[3] * s),
                     (int)cvt_pk(v[4] * s, v[5] * s), (int)cvt_pk(v[6] * s, v[7] * s));
}
__device__ __forceinline__ bf16x8 pk8(float4 a, float4 b) {
    u32x4 t;
    t[0] = cvt_pk(a.x, a.y); t[1] = cvt_pk(a.z, a.w);
    t[2] = cvt_pk(b.x, b.y); t[3] = cvt_pk(b.z, b.w);
    return __builtin_bit_cast(bf16x8, t);
}

} // namespace

__global__ void __launch_bounds__(512, 1)
rnn_fused(const float* __restrict__ x,    const float* __restrict__ Wih0,
          const float* __restrict__ Wih,  const float* __restrict__ Whh,
          const float* __restrict__ bih,  const float* __restrict__ bhh,
          const float* __restrict__ Wc,   const float* __restrict__ bc,
          float* __restrict__ out)
{
    extern __shared__ char smem[];
    const int tid  = threadIdx.x;
    const int lane = tid & 63;
    const int wid  = tid >> 6;          // wave 0..7
    const int sl   = lane & 15;         // seq-in-group / frag row
    const int g    = lane >> 4;         // lane group 0..3
    const int swzS = (sl & 7) << 4;     // LDS row XOR swizzle
    const int seqA = blockIdx.x * 256 + wid * 16 + sl;   // group A sequence
    // group B = seqA + 128 (waves 0..7 cover 0..127, B covers 128..255)

    const int rd0 = (g * 16) ^ swzS;        // B-frag k = g*8..g*8+7
    const int rd1 = (64 + g * 16) ^ swzS;   // B-frag k = 32+g*8..
    int wro[4];
#pragma unroll
    for (int jt = 0; jt < 4; ++jt) wro[jt] = (jt * 32 + g * 8) ^ swzS;
    const int scrA = SCR + (wid * 2) * 2048 + sl * 128;  // per-wave, per-group
    const int scrB = scrA + 2048;

    // ---------------- one-time staging: ALL weights -> LDS ----------------
    {
        const int j = tid >> 3, k0 = (tid & 7) * 8;
        const int wz = (k0 * 2) ^ ((j & 7) << 4);
#pragma unroll
        for (int l = 0; l < 7; ++l) {
            float v[8];
            if (l == 0) {   // Wih0 zero-padded [64][28->64]
#pragma unroll
                for (int e = 0; e < 8; ++e)
                    v[e] = (k0 + e < 28) ? Wih0[j * 28 + k0 + e] : 0.f;
            } else {
                const float* src = Wih + (size_t)(l - 1) * 4096 + j * 64 + k0;
                float4 a4 = *(const float4*)(src);
                float4 b4 = *(const float4*)(src + 4);
                v[0]=a4.x; v[1]=a4.y; v[2]=a4.z; v[3]=a4.w;
                v[4]=b4.x; v[5]=b4.y; v[6]=b4.z; v[7]=b4.w;
            }
            *(int4*)(smem + WST + l * 16384 + j * 128 + wz) = pack8s(v, TANH_K);
            const float* srh = Whh + (size_t)l * 4096 + j * 64 + k0;
            float4 a4 = *(const float4*)(srh);
            float4 b4 = *(const float4*)(srh + 4);
            float w[8] = {a4.x, a4.y, a4.z, a4.w, b4.x, b4.y, b4.z, b4.w};
            *(int4*)(smem + WST + l * 16384 + 8192 + j * 128 + wz) = pack8s(w, TANH_K);
        }
    }
    if (tid < 128) { // Wc zero-padded [16][64] (UNscaled: no tanh after)
        int c = tid >> 3, k0 = (tid & 7) * 8;
        float v[8];
#pragma unroll
        for (int e = 0; e < 8; ++e) v[e] = (c < 10) ? Wc[c * 64 + k0 + e] : 0.f;
        *(int4*)(smem + WCL + c * 128 + ((k0 * 2) ^ ((c & 7) << 4))) = pack8s(v, 1.f);
    }
    if (tid < 448) *(float*)(smem + BIA + tid * 4) = (bih[tid] + bhh[tid]) * TANH_K;
    if (tid < 16)  *(float*)(smem + BCV + tid * 4) = (tid < 10) ? bc[tid] : 0.f;
    __syncthreads();    // the ONLY barrier; main loop is wave-independent

    // ---------------- main loop: time outer, layer inner, 2 groups ----------
    const bf16x8 zf = {};
    bf16x8 hbA0[7], hbA1[7], hbB0[7], hbB1[7];   // h(l,t-1); static indices!
#pragma unroll
    for (int l = 0; l < 7; ++l) {
        hbA0[l] = zf; hbA1[l] = zf; hbB0[l] = zf; hbB1[l] = zf;
    }

    const float* xrA = x + (size_t)seqA * 784 + g * 8;
    const float* xrB = xrA + (size_t)128 * 784;
    const float4 z4 = make_float4(0.f, 0.f, 0.f, 0.f);

#pragma unroll 1
    for (int t = 0; t < 28; ++t) {
        // x B-frags straight from global; g=3 upper half (k=28..31) zeroed.
        const float* pA = xrA + t * 28;
        const float* pB = xrB + t * 28;
        float4 a0 = *(const float4*)(pA);
        float4 a1 = (g < 3) ? *(const float4*)(pA + 4) : z4;
        float4 b0 = *(const float4*)(pB);
        float4 b1 = (g < 3) ? *(const float4*)(pB + 4) : z4;
        const bf16x8 xtA = pk8(a0, a1);
        const bf16x8 xtB = pk8(b0, b1);

        bf16x8 itA0, itA1, itB0, itB1;   // layer-(l-1) output frags

#pragma unroll                  // FULL unroll: hb[l] + LDS offsets static
        for (int l = 0; l < 7; ++l) {
            const int wb = WST + l * 16384;
            bf16x8 wi0[4], wi1[4], wh0[4], wh1[4];
            f32x4  bs[4];
#pragma unroll
            for (int jt = 0; jt < 4; ++jt) {
                const int ro = wb + (jt * 16 + sl) * 128;
                wi0[jt] = *(const bf16x8*)(smem + ro + rd0);
                if (l) wi1[jt] = *(const bf16x8*)(smem + ro + rd1); // l=0: zero cols
                wh0[jt] = *(const bf16x8*)(smem + ro + 8192 + rd0);
                wh1[jt] = *(const bf16x8*)(smem + ro + 8192 + rd1);
                bs[jt]  = *(const f32x4*)(smem + BIA + l * 256 + jt * 64 + g * 16);
            }
            const bf16x8 iA0 = l ? itA0 : xtA, iA1 = l ? itA1 : zf;
            const bf16x8 iB0 = l ? itB0 : xtB, iB1 = l ? itB1 : zf;

            // two independent MFMA->tanh->relayout chains, interleaved per jt
#pragma unroll
            for (int jt = 0; jt < 4; ++jt) {
                f32x4 a = bs[jt];
                a = __builtin_amdgcn_mfma_f32_16x16x32_bf16(wi0[jt], iA0, a, 0, 0, 0);
                if (l) a = __builtin_amdgcn_mfma_f32_16x16x32_bf16(wi1[jt], iA1, a, 0, 0, 0);
                a = __builtin_amdgcn_mfma_f32_16x16x32_bf16(wh0[jt], hbA0[l], a, 0, 0, 0);
                a = __builtin_amdgcn_mfma_f32_16x16x32_bf16(wh1[jt], hbA1[l], a, 0, 0, 0);
                f32x4 b = bs[jt];
                b = __builtin_amdgcn_mfma_f32_16x16x32_bf16(wi0[jt], iB0, b, 0, 0, 0);
                if (l) b = __builtin_amdgcn_mfma_f32_16x16x32_bf16(wi1[jt], iB1, b, 0, 0, 0);
                b = __builtin_amdgcn_mfma_f32_16x16x32_bf16(wh0[jt], hbB0[l], b, 0, 0, 0);
                b = __builtin_amdgcn_mfma_f32_16x16x32_bf16(wh1[jt], hbB1[l], b, 0, 0, 0);
                unsigned qa0 = cvt_pk(tanh_pre(a[0]), tanh_pre(a[1]));
                unsigned qa1 = cvt_pk(tanh_pre(a[2]), tanh_pre(a[3]));
                *(int2*)(smem + scrA + wro[jt]) = make_int2((int)qa0, (int)qa1);
                unsigned qb0 = cvt_pk(tanh_pre(b[0]), tanh_pre(b[1]));
                unsigned qb1 = cvt_pk(tanh_pre(b[2]), tanh_pre(b[3]));
                *(int2*)(smem + scrB + wro[jt]) = make_int2((int)qb0, (int)qb1);
            }
            const bf16x8 nA0 = *(const bf16x8*)(smem + scrA + rd0);
            const bf16x8 nA1 = *(const bf16x8*)(smem + scrA + rd1);
            const bf16x8 nB0 = *(const bf16x8*)(smem + scrB + rd0);
            const bf16x8 nB1 = *(const bf16x8*)(smem + scrB + rd1);
            hbA0[l] = nA0; hbA1[l] = nA1; itA0 = nA0; itA1 = nA1;
            hbB0[l] = nB0; hbB1[l] = nB1; itB0 = nB0; itB1 = nB1;
        }
    }

    // ---------------- classifier: out = h6(t=27) @ Wc^T + bc ----------------
    {
        const int ro = WCL + sl * 128;                   // A row = class c = sl
        bf16x8 w0 = *(const bf16x8*)(smem + ro + rd0);
        bf16x8 w1 = *(const bf16x8*)(smem + ro + rd1);
        f32x4 oA = {0.f, 0.f, 0.f, 0.f}, oB = {0.f, 0.f, 0.f, 0.f};
        oA = __builtin_amdgcn_mfma_f32_16x16x32_bf16(w0, hbA0[6], oA, 0, 0, 0);
        oA = __builtin_amdgcn_mfma_f32_16x16x32_bf16(w1, hbA1[6], oA, 0, 0, 0);
        oB = __builtin_amdgcn_mfma_f32_16x16x32_bf16(w0, hbB0[6], oB, 0, 0, 0);
        oB = __builtin_amdgcn_mfma_f32_16x16x32_bf16(w1, hbB1[6], oB, 0, 0, 0);
        f32x4 bb = *(const f32x4*)(smem + BCV + g * 16);
#pragma unroll
        for (int r = 0; r < 4; ++r) {
            const int c = g * 4 + r;
            if (c < 10) {
                out[(size_t)seqA * 10 + c]         = oA[r] + bb[r];
                out[(size_t)(seqA + 128) * 10 + c] = oB[r] + bb[r];
            }
        }
    }
}

extern "C" void kernel_launch(void* const* d_in, const int* in_sizes, int n_in,
                              void* d_out, int out_size, void* d_ws, size_t ws_size,
                              hipStream_t stream) {
    (void)in_sizes; (void)n_in; (void)d_ws; (void)ws_size; (void)out_size;
    hipFuncSetAttribute((const void*)rnn_fused,
                        hipFuncAttributeMaxDynamicSharedMemorySize, LDS_TOTAL);
    rnn_fused<<<dim3(256), dim3(512), LDS_TOTAL, stream>>>(
        (const float*)d_in[0], (const float*)d_in[1], (const float*)d_in[2],
        (const float*)d_in[3], (const float*)d_in[4], (const float*)d_in[5],
        (const float*)d_in[6], (const float*)d_in[7], (float*)d_out);
}